// Round 9
// baseline (777.129 us; speedup 1.0000x reference)
//
#include <hip/hip_runtime.h>
#include <hip/hip_bf16.h>

#define DE 1024
#define DM 64
#define DC 128
#define DX 1152      // DE+DC
#define NB 4
#define NN 4096
#define NT 16384     // NB*NN

typedef _Float16 f16;
typedef _Float16 f16x4 __attribute__((ext_vector_type(4)));
typedef _Float16 f16x8 __attribute__((ext_vector_type(8)));
typedef float f32x4 __attribute__((ext_vector_type(4)));

__device__ __forceinline__ void g2l16(const void* g, void* l) {
  __builtin_amdgcn_global_load_lds(
      (const __attribute__((address_space(1))) unsigned int*)(unsigned long long)g,
      (__attribute__((address_space(3))) unsigned int*)(unsigned int)(unsigned long long)l,
      16, 0, 0);
}

// ---------------- prep kernels ----------------
__global__ void build_x_kernel(const float* __restrict__ e, const float* __restrict__ c,
                               f16* __restrict__ Xb) {
  const int total = NT * DX / 4;
  for (int i = blockIdx.x * blockDim.x + threadIdx.x; i < total; i += gridDim.x * blockDim.x) {
    int idx = i * 4;
    int r = idx / DX, col = idx - r * DX;
    float4 v;
    if (col < DE) v = *(const float4*)(e + (long)r * DE + col);
    else          v = *(const float4*)(c + (long)r * DC + (col - DE));
    f16x4 o = { (f16)v.x, (f16)v.y, (f16)v.z, (f16)v.w };
    *(f16x4*)(Xb + (long)idx) = o;
  }
}

__global__ void conv_f16_kernel(const float* __restrict__ in, f16* __restrict__ out, int total4) {
  for (int i = blockIdx.x * blockDim.x + threadIdx.x; i < total4; i += gridDim.x * blockDim.x) {
    float4 v = *(const float4*)(in + (long)i * 4);
    f16x4 o = { (f16)v.x, (f16)v.y, (f16)v.z, (f16)v.w };
    *(f16x4*)(out + (long)i * 4) = o;
  }
}

// in [DX][DE] f32  ->  out [DE][DX] f16
__global__ void transpose_w_kernel(const float* __restrict__ in, f16* __restrict__ out) {
  __shared__ float tile[32][33];
  int c0 = blockIdx.x * 32, r0 = blockIdx.y * 32;
  int x = threadIdx.x, y = threadIdx.y;   // block (32,8)
#pragma unroll
  for (int i = 0; i < 4; ++i)
    tile[y + 8 * i][x] = in[(long)(r0 + y + 8 * i) * DE + (c0 + x)];
  __syncthreads();
#pragma unroll
  for (int i = 0; i < 4; ++i)
    out[(long)(c0 + y + 8 * i) * DX + (r0 + x)] = (f16)tile[x][y + 8 * i];
}

// ---------------- 128^2 GEMM core: m97 structure + conflict-free swizzle ----
// C[128x128] += A[128xK]*B[128xK]^T; 256 thr = 4 waves (2Mx2N), per-wave
// 64x64 = acc[4][4] of 16x16x32 f16 MFMA. LDS: SINGLE buffer 16KB A + 16KB B
// = 32KB -> ~5 blocks/CU. Strict 2-barrier alternation per K-tile (BK=64):
//   sync; stage(tt); sync(drains vm+lgkm); frag reads + 32 MFMA.
// NO manual waits -- all overlap comes from co-resident blocks (m97/m114).
// Conflict-free ds_read via source-side XOR swizzle (byte bits 4-6 ^= row&7);
// LDS dest stays linear (global_load_lds requirement).
__device__ __forceinline__ void gemm4_core(
    const f16* __restrict__ A, long lda,
    const f16* __restrict__ B, long ldb,
    int NTt, char* ldsb, f32x4 (&acc)[4][4]) {
  const int tid = threadIdx.x;          // 0..255
  const int lane = tid & 63, wid = tid >> 6;
  const int wr = wid >> 1, wc = wid & 1;
  const int fr = lane & 15, fq = lane >> 4;
  const int cb0 = ((fq) ^ (fr & 7)) << 4;        // swizzled byte col, ks=0
  const int cb1 = ((4 | fq) ^ (fr & 7)) << 4;    // ks=1

  auto stage = [&](const f16* __restrict__ S, long ld, int kt, char* base) {
#pragma unroll
    for (int it = 0; it < 4; ++it) {
      int off = it * 4096 + tid * 16;            // linear LDS byte offset
      int sw = off ^ (((off >> 7) & 7) << 4);    // pre-swizzled source addr
      int row = sw >> 7;                         // 0..127
      int colf = ((sw >> 4) & 7) << 3;           // f16 col 0..56
      g2l16(S + (long)row * ld + kt * 64 + colf, base + off);
    }
  };

  for (int tt = 0; tt < NTt; ++tt) {
    __syncthreads();                     // all waves done reading prev tile
    stage(A, lda, tt, ldsb);
    stage(B, ldb, tt, ldsb + 16384);
    __syncthreads();                     // staging landed (vm+lgkm drained)
    f16x8 a[4][2], b[4][2];
#pragma unroll
    for (int i = 0; i < 4; ++i) {
      int row = wr * 64 + i * 16 + fr;
      a[i][0] = *(const f16x8*)(const void*)(ldsb + row * 128 + cb0);
      a[i][1] = *(const f16x8*)(const void*)(ldsb + row * 128 + cb1);
    }
#pragma unroll
    for (int i = 0; i < 4; ++i) {
      int row = wc * 64 + i * 16 + fr;
      b[i][0] = *(const f16x8*)(const void*)(ldsb + 16384 + row * 128 + cb0);
      b[i][1] = *(const f16x8*)(const void*)(ldsb + 16384 + row * 128 + cb1);
    }
    __builtin_amdgcn_s_setprio(1);
#pragma unroll
    for (int k = 0; k < 2; ++k)          // k-outer: no same-acc back-to-back
#pragma unroll
      for (int m = 0; m < 4; ++m)
#pragma unroll
        for (int n = 0; n < 4; ++n)
          acc[m][n] = __builtin_amdgcn_mfma_f32_16x16x32_f16(a[m][k], b[n][k], acc[m][n], 0, 0, 0);
    __builtin_amdgcn_s_setprio(0);
  }
}

__device__ __forceinline__ void swz_grid(int& bx, int& by, int& bz) {
  int nx = gridDim.x, ny = gridDim.y;
  int flat = blockIdx.x + nx * (blockIdx.y + ny * blockIdx.z);
  int total = nx * ny * gridDim.z;
  int cpx = total >> 3;               // all grids are multiples of 8
  flat = (flat & 7) * cpx + (flat >> 3);
  bx = flat % nx; int r = flat / nx;
  by = r % ny; bz = r / ny;
}

#define ACC_INIT(nm)                                                \
  f32x4 nm[4][4];                                                   \
  _Pragma("unroll") for (int m_ = 0; m_ < 4; ++m_)                  \
  _Pragma("unroll") for (int n_ = 0; n_ < 4; ++n_)                  \
      nm[m_][n_] = (f32x4){0.f, 0.f, 0.f, 0.f};

#define EPI4_IDX()                                                  \
  const int lane = threadIdx.x & 63, wid = threadIdx.x >> 6;        \
  const int wr = wid >> 1, wc = wid & 1;                            \
  const int fr = lane & 15, fq = lane >> 4;

// q,k projection: M=16384, N=2048 (q|k), K=1152. grid (128,16)
__global__ __launch_bounds__(256) void qk8_kernel(
    const f16* __restrict__ Xb, const f16* __restrict__ Wt,
    const float* __restrict__ bq, const float* __restrict__ bk,
    f16* __restrict__ qb, f16* __restrict__ kb) {
  __shared__ __attribute__((aligned(128))) char ldsb[32768];
  int bx, by, bz; swz_grid(bx, by, bz);
  const int row0 = bx * 128, col0 = by * 128;
  ACC_INIT(acc);
  gemm4_core(Xb + (long)row0 * DX, DX, Wt + (long)col0 * DX, DX, DX / 64, ldsb, acc);
  EPI4_IDX();
  const bool isq = col0 < DE;
  const float* bvec = isq ? bq : bk;
  f16* ob = isq ? qb : kb;
  const int cbase = (isq ? col0 : col0 - DE) + wc * 64;
  const int rbase = row0 + wr * 64;
#pragma unroll
  for (int n = 0; n < 4; ++n) {
    int col = cbase + n * 16 + fr;
    float bb = bvec[col];
#pragma unroll
    for (int m = 0; m < 4; ++m)
#pragma unroll
      for (int j = 0; j < 4; ++j) {
        int row = rbase + m * 16 + fq * 4 + j;
        ob[(long)row * DE + col] = (f16)(acc[m][n][j] + bb);
      }
  }
}

// Vt[d][token]: M=1024 (d), N=16384 (tokens), K=1152. grid (8,128)
__global__ __launch_bounds__(256) void vt8_kernel(
    const f16* __restrict__ WtV, const f16* __restrict__ Xb,
    const float* __restrict__ bv, f16* __restrict__ Vt) {
  __shared__ __attribute__((aligned(128))) char ldsb[32768];
  int bx, by, bz; swz_grid(bx, by, bz);
  const int row0 = bx * 128, col0 = by * 128;
  ACC_INIT(acc);
  gemm4_core(WtV + (long)row0 * DX, DX, Xb + (long)col0 * DX, DX, DX / 64, ldsb, acc);
  EPI4_IDX();
  const int cbase = col0 + wc * 64;
  const int rbase = row0 + wr * 64;
#pragma unroll
  for (int n = 0; n < 4; ++n) {
    int col = cbase + n * 16 + fr;
#pragma unroll
    for (int m = 0; m < 4; ++m)
#pragma unroll
      for (int j = 0; j < 4; ++j) {
        int row = rbase + m * 16 + fq * 4 + j;
        Vt[(long)row * NT + col] = (f16)(acc[m][n][j] + bv[row]);
      }
  }
}

// masked scores per batch: S = (q.k/32) * (m.m) * l_r*l_c (fp32). grid (32,32)
// mask GEMM fused: DM=64 = exactly one BK=64 tile -> second gemm4_core call.
__global__ __launch_bounds__(256) void sc8_kernel(
    const f16* __restrict__ qb_, const f16* __restrict__ kb_,
    const f16* __restrict__ mb_, const float* __restrict__ l_,
    float* __restrict__ S) {
  __shared__ __attribute__((aligned(128))) char ldsb[32768];
  int bx, by, bz; swz_grid(bx, by, bz);
  const int row0 = bx * 128, col0 = by * 128;
  ACC_INIT(acc);
  gemm4_core(qb_ + (long)row0 * DE, DE, kb_ + (long)col0 * DE, DE, DE / 64, ldsb, acc);
  ACC_INIT(am);
  gemm4_core(mb_ + (long)row0 * DM, DM, mb_ + (long)col0 * DM, DM, 1, ldsb, am);
  EPI4_IDX();
  const int cbase = col0 + wc * 64;
  const int rbase = row0 + wr * 64;
  const float scale = 0.03125f;
#pragma unroll
  for (int n = 0; n < 4; ++n) {
    int col = cbase + n * 16 + fr;
    float lc = l_[col] * scale;
#pragma unroll
    for (int m = 0; m < 4; ++m)
#pragma unroll
      for (int j = 0; j < 4; ++j) {
        int row = rbase + m * 16 + fq * 4 + j;
        S[(long)row * NN + col] = acc[m][n][j] * am[m][n][j] * lc * l_[row];
      }
  }
}

// h = P @ V (K=4096); outE = e + h, outH = h. grid (32,8,4)
__global__ __launch_bounds__(256) void pv8_kernel(
    const f16* __restrict__ P, const f16* __restrict__ Vt,
    const float* __restrict__ e, float* __restrict__ outE, float* __restrict__ outH) {
  __shared__ __attribute__((aligned(128))) char ldsb[32768];
  int bx, by, bz; swz_grid(bx, by, bz);
  const int b = bz;
  const int row0 = bx * 128, col0 = by * 128;
  ACC_INIT(acc);
  gemm4_core(P + (long)b * NN * NN + (long)row0 * NN, NN,
             Vt + (long)col0 * NT + (long)b * NN, NT, NN / 64, ldsb, acc);
  EPI4_IDX();
  const int cbase = col0 + wc * 64;
  const int rbase = row0 + wr * 64;
#pragma unroll
  for (int n = 0; n < 4; ++n) {
    int col = cbase + n * 16 + fr;
#pragma unroll
    for (int m = 0; m < 4; ++m)
#pragma unroll
      for (int j = 0; j < 4; ++j) {
        int row = rbase + m * 16 + fq * 4 + j;
        long idx = ((long)b * NN + row) * DE + col;
        float h = acc[m][n][j];
        outE[idx] = e[idx] + h;
        outH[idx] = h;
      }
  }
}

// row softmax: S fp32 (mask pre-applied) -> P f16. one block per row
__global__ __launch_bounds__(256) void softmax_kernel(const float* __restrict__ S,
                                                      f16* __restrict__ P) {
  __shared__ float red[8];
  const long row = blockIdx.x;
  const float* s = S + row * NN;
  const int t = threadIdx.x;
  float4 v[4];
  float mx = -3.0e38f;
#pragma unroll
  for (int i = 0; i < 4; ++i) {
    v[i] = *(const float4*)(s + t * 4 + i * 1024);
    mx = fmaxf(mx, fmaxf(fmaxf(v[i].x, v[i].y), fmaxf(v[i].z, v[i].w)));
  }
#pragma unroll
  for (int o = 32; o; o >>= 1) mx = fmaxf(mx, __shfl_xor(mx, o));
  if ((t & 63) == 0) red[t >> 6] = mx;
  __syncthreads();
  mx = fmaxf(fmaxf(red[0], red[1]), fmaxf(red[2], red[3]));
  float sum = 0.f;
#pragma unroll
  for (int i = 0; i < 4; ++i) {
    v[i].x = __expf(v[i].x - mx); v[i].y = __expf(v[i].y - mx);
    v[i].z = __expf(v[i].z - mx); v[i].w = __expf(v[i].w - mx);
    sum += v[i].x + v[i].y + v[i].z + v[i].w;
  }
#pragma unroll
  for (int o = 32; o; o >>= 1) sum += __shfl_xor(sum, o);
  if ((t & 63) == 0) red[4 + (t >> 6)] = sum;
  __syncthreads();
  float inv = 1.f / (red[4] + red[5] + red[6] + red[7]);
  f16* p = P + row * NN;
#pragma unroll
  for (int i = 0; i < 4; ++i) {
    f16x4 o4 = { (f16)(v[i].x * inv), (f16)(v[i].y * inv),
                 (f16)(v[i].z * inv), (f16)(v[i].w * inv) };
    *(f16x4*)(p + t * 4 + i * 1024) = o4;
  }
}

extern "C" void kernel_launch(void* const* d_in, const int* in_sizes, int n_in,
                              void* d_out, int out_size, void* d_ws, size_t ws_size,
                              hipStream_t stream) {
  const float* e  = (const float*)d_in[0];
  const float* m  = (const float*)d_in[1];
  const float* c  = (const float*)d_in[2];
  const float* l  = (const float*)d_in[3];
  const float* Wq = (const float*)d_in[4];
  const float* bq = (const float*)d_in[5];
  const float* Wk = (const float*)d_in[6];
  const float* bk = (const float*)d_in[7];
  const float* Wv = (const float*)d_in[8];
  const float* bv = (const float*)d_in[9];
  float* outE = (float*)d_out;
  float* outH = outE + (long)NT * DE;

  char* ws = (char*)d_ws;
  size_t off = 0;
  auto alloc = [&](size_t bytes) {
    char* p = ws + off;
    off += (bytes + 255) & ~(size_t)255;
    return p;
  };
  f16* Xb    = (f16*)alloc((size_t)NT * DX * 2);
  f16* WtQK  = (f16*)alloc((size_t)2048 * DX * 2);
  f16* WtV   = (f16*)alloc((size_t)DE * DX * 2);
  f16* qb    = (f16*)alloc((size_t)NT * DE * 2);
  f16* kb    = (f16*)alloc((size_t)NT * DE * 2);
  f16* Vt    = (f16*)alloc((size_t)DE * NT * 2);
  f16* mb    = (f16*)alloc((size_t)NT * DM * 2);
  float* S   = (float*)alloc((size_t)NN * NN * 4);
  f16* P     = (f16*)alloc((size_t)NB * NN * NN * 2);
  if (off > ws_size) return;

  build_x_kernel<<<2048, 256, 0, stream>>>(e, c, Xb);
  conv_f16_kernel<<<512, 256, 0, stream>>>(m, mb, NT * DM / 4);
  transpose_w_kernel<<<dim3(32, 36), dim3(32, 8), 0, stream>>>(Wq, WtQK);
  transpose_w_kernel<<<dim3(32, 36), dim3(32, 8), 0, stream>>>(Wk, WtQK + (size_t)DE * DX);
  transpose_w_kernel<<<dim3(32, 36), dim3(32, 8), 0, stream>>>(Wv, WtV);
  qk8_kernel<<<dim3(128, 16), 256, 0, stream>>>(Xb, WtQK, bq, bk, qb, kb);
  vt8_kernel<<<dim3(8, 128), 256, 0, stream>>>(WtV, Xb, bv, Vt);
  for (int b = 0; b < NB; ++b) {
    sc8_kernel<<<dim3(32, 32), 256, 0, stream>>>(
        qb + (size_t)b * NN * DE, kb + (size_t)b * NN * DE,
        mb + (size_t)b * NN * DM, l + (size_t)b * NN, S);
    softmax_kernel<<<NN, 256, 0, stream>>>(S, P + (size_t)b * NN * NN);
  }
  pv8_kernel<<<dim3(32, 8, NB), 256, 0, stream>>>(P, Vt, e, outE, outH);
}